// Round 9
// baseline (23.560 us; speedup 1.0000x reference)
//
#include <hip/hip_runtime.h>
#include <math.h>

// Problem constants
#define B_  32
#define D_  64
#define L_  4096
#define E_  8
#define OC_ 32
#define LP_ 4094   // L - 2 (VALID conv, kernel 3)
#define TILE 128
#define NT   32    // tiles per batch (4096/128)

typedef __attribute__((ext_vector_type(8)))  short short8;
typedef __attribute__((ext_vector_type(16))) float float16;

static __device__ __forceinline__ unsigned short f2bf(float f) {
    unsigned u = __float_as_uint(f);
    return (unsigned short)((u + 0x7fffu + ((u >> 16) & 1u)) >> 16);
}
// packed f32x2 -> bf16x2 (low = a, high = b) in ONE instruction
static __device__ __forceinline__ unsigned cvtpk(float a, float b) {
    unsigned r;
    asm("v_cvt_pk_bf16_f32 %0, %1, %2" : "=v"(r) : "v"(a), "v"(b));
    return r;
}
// tanh via hw exp + rcp: 1 - 2/(e^{2x}+1)   (~5 VALU ops, err ~1e-5)
static __device__ __forceinline__ float fast_tanh(float x) {
    float e = __expf(2.0f * x);
    return fmaf(-2.0f, __builtin_amdgcn_rcpf(e + 1.0f), 1.0f);
}

// ---------------------------------------------------------------------------
// Workspace: beff f32[32][32] @0 (4KB) | aF bf16[12][64][8] @4096 (12KB)
//            wf2 bf16[B][2][64][8] @16384 (64KB)
// ---------------------------------------------------------------------------

// Prep: blocks 0..7 (wave w -> batch 4*blk+w): gates + Weff frags + beff.
//       block 8: conv1 A-fragments.
__global__ __launch_bounds__(256)
void prep_kernel(const float* __restrict__ x,
                 const float* __restrict__ w_gate,
                 const float* __restrict__ c1w,
                 const float* __restrict__ c2w,
                 const float* __restrict__ c2b,
                 float* __restrict__ beff,
                 unsigned short* __restrict__ aF,
                 unsigned short* __restrict__ wf2)
{
    const int tid = threadIdx.x;

    if (blockIdx.x == 8) {
        for (int i = tid; i < 12 * 64 * 8; i += 256) {
            int ks = i >> 9, lane = (i >> 3) & 63, ii = i & 7;
            int oc = lane & 31, half = lane >> 5;
            int kp = ks * 16 + half * 8 + ii;
            int t = kp >> 6, c = kp & 63;
            aF[i] = f2bf(c1w[oc * 192 + c * 3 + t]);
        }
        return;
    }

    const int wv = tid >> 6, lane = tid & 63;
    const int b  = blockIdx.x * 4 + wv;
    const int d  = lane;

    float xv[5];
    #pragma unroll
    for (int t = 0; t < 5; ++t)
        xv[t] = x[((size_t)b * D_ + d) * L_ + (L_ - 6) + t];

    float part[E_];
    #pragma unroll
    for (int e = 0; e < E_; ++e) part[e] = 0.f;
    #pragma unroll
    for (int t = 0; t < 5; ++t) {
        const float* wg = w_gate + (d * 5 + t) * E_;
        #pragma unroll
        for (int e = 0; e < E_; ++e) part[e] += xv[t] * wg[e];
    }
    #pragma unroll
    for (int off = 1; off < 64; off <<= 1) {
        #pragma unroll
        for (int e = 0; e < E_; ++e)
            part[e] += __shfl_xor(part[e], off, 64);
    }
    float m = part[0];
    #pragma unroll
    for (int e = 1; e < E_; ++e) m = fmaxf(m, part[e]);
    float p[E_], s = 0.f;
    #pragma unroll
    for (int e = 0; e < E_; ++e) { p[e] = expf(part[e] - m); s += p[e]; }
    float inv = 1.f / s;
    #pragma unroll
    for (int e = 0; e < E_; ++e) p[e] *= inv;

    int i0 = 0;
    #pragma unroll
    for (int e = 1; e < E_; ++e) if (p[e] > p[i0]) i0 = e;
    int i1 = (i0 == 0) ? 1 : 0;
    #pragma unroll
    for (int e = 0; e < E_; ++e) {
        if (e == i0) continue;
        if (p[e] > p[i1]) i1 = e;
    }
    const float v0 = p[i0], v1 = p[i1];
    const float den = v0 + v1 + 1e-6f;
    const float g0 = v0 / den, g1 = v1 / den;

    // Weff A-frags: A[m=dd=cl][k=oc], oc = ks*16 + (lane>>5)*8 + i
    {
        const int dd = lane & 31, half = lane >> 5;
        #pragma unroll
        for (int ks = 0; ks < 2; ++ks) {
            #pragma unroll
            for (int i = 0; i < 8; ++i) {
                int oc = ks * 16 + half * 8 + i;
                float v = g0 * c2w[(dd * E_ + i0) * OC_ + oc]
                        + g1 * c2w[(dd * E_ + i1) * OC_ + oc];
                wf2[((b * 2 + ks) * 64 + lane) * 8 + i] = f2bf(v);
            }
        }
    }
    if (d < OC_)
        beff[b * OC_ + d] = g0 * c2b[d * E_ + i0] + g1 * c2b[d * E_ + i1];
}

// ---------------------------------------------------------------------------
// Fused main v3: NO LDS, NO BARRIER. Pure streaming implicit-GEMM conv.
// B-fragments loaded directly from global x: for fragment (t,q), lane (cl,hi)
// needs x[q*16+hi*8+i][l+t] (i=0..7): fixed i -> 32 consecutive floats across
// the half-wave (coalesced 128 B); 3 taps share L1 lines. Latency hidden by
// TLP (16 waves/CU) + MLP (27 independent loads per q-step), not barriers.
// Block = (batch, 128-col tile); 4 waves, one 32-col MFMA tile each.
// ---------------------------------------------------------------------------
__global__ __launch_bounds__(256, 4)
void fused_main(const float* __restrict__ x,
                const unsigned short* __restrict__ aF,   // [12][64][8]
                const unsigned short* __restrict__ wf2,  // [B][2][64][8]
                const float* __restrict__ beff,          // [B][32]
                const float* __restrict__ c1b,           // [32]
                float* __restrict__ out)                 // [B][32][4094]
{
    const int tid  = threadIdx.x;
    const int lane = tid & 63;
    const int wv   = tid >> 6;
    const int b    = blockIdx.x >> 5;
    const int l0   = (blockIdx.x & 31) << 7;
    const float* xb = x + (size_t)b * (D_ * L_);

    const int cl = lane & 31;
    const int hi = lane >> 5;
    const int cb = wv * 32;

    const int l  = l0 + cb + cl;
    // dead lanes (l >= LP_) clamp their load address; taps reach lc+2 <= 4095
    const int lc = (l > L_ - 3) ? (L_ - 3) : l;

    // ---- conv1: 12 x mfma_32x32x16_bf16, B-operands straight from global ----
    float16 acc = (float16)0.0f;
    #pragma unroll
    for (int q = 0; q < 4; ++q) {
        const float* xc = xb + (size_t)(q * 16 + hi * 8) * L_ + lc;
        float v0[8], v1[8], v2[8];
        #pragma unroll
        for (int i = 0; i < 8; ++i) {
            const float* p = xc + (size_t)i * L_;
            v0[i] = p[0];
            v1[i] = p[1];
            v2[i] = p[2];
        }
        short8 a0 = *(const short8*)(aF + ((0 * 4 + q) * 64 + lane) * 8);
        short8 a1 = *(const short8*)(aF + ((1 * 4 + q) * 64 + lane) * 8);
        short8 a2t = *(const short8*)(aF + ((2 * 4 + q) * 64 + lane) * 8);
        union { short8 s8; unsigned u[4]; } f0, f1, f2;
        #pragma unroll
        for (int j = 0; j < 4; ++j) {
            f0.u[j] = cvtpk(v0[2 * j], v0[2 * j + 1]);
            f1.u[j] = cvtpk(v1[2 * j], v1[2 * j + 1]);
            f2.u[j] = cvtpk(v2[2 * j], v2[2 * j + 1]);
        }
        acc = __builtin_amdgcn_mfma_f32_32x32x16_bf16(a0,  f0.s8, acc, 0, 0, 0);
        acc = __builtin_amdgcn_mfma_f32_32x32x16_bf16(a1,  f1.s8, acc, 0, 0, 0);
        acc = __builtin_amdgcn_mfma_f32_32x32x16_bf16(a2t, f2.s8, acc, 0, 0, 0);
    }

    // conv2 A-frags (L2-hot)
    short8 a2[2];
    a2[0] = *(const short8*)(wf2 + ((b * 2 + 0) * 64 + lane) * 8);
    a2[1] = *(const short8*)(wf2 + ((b * 2 + 1) * 64 + lane) * 8);

    // ---- bias + fast tanh ----
    float th[16];
    #pragma unroll
    for (int r = 0; r < 16; ++r) {
        int row = (r & 3) + 8 * (r >> 2) + 4 * hi;
        th[r] = fast_tanh(acc[r] + c1b[row]);
    }

    // ---- conv2 B-frags in-register via half-wave swap (lane ^ 32) ----
    unsigned x0a = hi ? cvtpk(th[0],  th[1])  : cvtpk(th[4],  th[5]);
    unsigned x0b = hi ? cvtpk(th[2],  th[3])  : cvtpk(th[6],  th[7]);
    unsigned x1a = hi ? cvtpk(th[8],  th[9])  : cvtpk(th[12], th[13]);
    unsigned x1b = hi ? cvtpk(th[10], th[11]) : cvtpk(th[14], th[15]);
    unsigned r0a = (unsigned)__shfl_xor((int)x0a, 32, 64);
    unsigned r0b = (unsigned)__shfl_xor((int)x0b, 32, 64);
    unsigned r1a = (unsigned)__shfl_xor((int)x1a, 32, 64);
    unsigned r1b = (unsigned)__shfl_xor((int)x1b, 32, 64);

    union U { short8 s8; unsigned u[4]; };
    U b0, b1;
    b0.u[0] = hi ? r0a : cvtpk(th[0], th[1]);
    b0.u[1] = hi ? r0b : cvtpk(th[2], th[3]);
    b0.u[2] = hi ? cvtpk(th[4], th[5]) : r0a;
    b0.u[3] = hi ? cvtpk(th[6], th[7]) : r0b;
    b1.u[0] = hi ? r1a : cvtpk(th[8], th[9]);
    b1.u[1] = hi ? r1b : cvtpk(th[10], th[11]);
    b1.u[2] = hi ? cvtpk(th[12], th[13]) : r1a;
    b1.u[3] = hi ? cvtpk(th[14], th[15]) : r1b;

    float16 acc2 = (float16)0.0f;
    acc2 = __builtin_amdgcn_mfma_f32_32x32x16_bf16(a2[0], b0.s8, acc2, 0, 0, 0);
    acc2 = __builtin_amdgcn_mfma_f32_32x32x16_bf16(a2[1], b1.s8, acc2, 0, 0, 0);

    // ---- direct stores (128B chunk per half-wave row) ----
    if (l < LP_) {
        const float* be = beff + b * OC_;
        float* ob = out + (size_t)b * (OC_ * (size_t)LP_) + l;
        #pragma unroll
        for (int r = 0; r < 16; ++r) {
            int row = (r & 3) + 8 * (r >> 2) + 4 * hi;
            ob[(size_t)row * LP_] = acc2[r] + be[row];
        }
    }
}

// ---------------------------------------------------------------------------
extern "C" void kernel_launch(void* const* d_in, const int* in_sizes, int n_in,
                              void* d_out, int out_size, void* d_ws, size_t ws_size,
                              hipStream_t stream)
{
    const float* x      = (const float*)d_in[0];
    const float* w_gate = (const float*)d_in[1];
    const float* c1w    = (const float*)d_in[2];
    const float* c1b    = (const float*)d_in[3];
    const float* c2w    = (const float*)d_in[4];
    const float* c2b    = (const float*)d_in[5];
    float* out = (float*)d_out;

    char* ws = (char*)d_ws;
    float* beff         = (float*)ws;                    // 4096 B
    unsigned short* aF  = (unsigned short*)(ws + 4096);  // 12288 B
    unsigned short* wf2 = (unsigned short*)(ws + 16384); // 65536 B

    prep_kernel<<<9, 256, 0, stream>>>(x, w_gate, c1w, c2w, c2b, beff, aF, wf2);
    fused_main<<<B_ * NT, 256, 0, stream>>>(x, aF, wf2, beff, c1b, out);
}

// Round 10
// 22.753 us; speedup vs baseline: 1.0355x; 1.0355x over previous
//
#include <hip/hip_runtime.h>
#include <math.h>

// Problem constants
#define B_  32
#define D_  64
#define L_  4096
#define E_  8
#define OC_ 32
#define LP_ 4094   // L - 2 (VALID conv, kernel 3)

typedef __attribute__((ext_vector_type(8)))  short short8;
typedef __attribute__((ext_vector_type(16))) float float16;

static __device__ __forceinline__ unsigned short f2bf(float f) {
    unsigned u = __float_as_uint(f);
    return (unsigned short)((u + 0x7fffu + ((u >> 16) & 1u)) >> 16);
}
static __device__ __forceinline__ unsigned cvtpk(float a, float b) {
    unsigned r;
    asm("v_cvt_pk_bf16_f32 %0, %1, %2" : "=v"(r) : "v"(a), "v"(b));
    return r;
}
static __device__ __forceinline__ float fast_tanh(float x) {
    float e = __expf(2.0f * x);
    return fmaf(-2.0f, __builtin_amdgcn_rcpf(e + 1.0f), 1.0f);
}

// ---------------------------------------------------------------------------
// Workspace: beff f32[32][32] @0 (4KB) | aF bf16[12][64][8] @4096 (12KB)
//            wf2 bf16[B][2][64][8] @16384 (64KB)
// ---------------------------------------------------------------------------
__global__ __launch_bounds__(256)
void prep_kernel(const float* __restrict__ x,
                 const float* __restrict__ w_gate,
                 const float* __restrict__ c1w,
                 const float* __restrict__ c2w,
                 const float* __restrict__ c2b,
                 float* __restrict__ beff,
                 unsigned short* __restrict__ aF,
                 unsigned short* __restrict__ wf2)
{
    const int tid = threadIdx.x;

    if (blockIdx.x == 8) {
        for (int i = tid; i < 12 * 64 * 8; i += 256) {
            int ks = i >> 9, lane = (i >> 3) & 63, ii = i & 7;
            int oc = lane & 31, half = lane >> 5;
            int kp = ks * 16 + half * 8 + ii;
            int t = kp >> 6, c = kp & 63;
            aF[i] = f2bf(c1w[oc * 192 + c * 3 + t]);
        }
        return;
    }

    const int wv = tid >> 6, lane = tid & 63;
    const int b  = blockIdx.x * 4 + wv;
    const int d  = lane;

    float xv[5];
    #pragma unroll
    for (int t = 0; t < 5; ++t)
        xv[t] = x[((size_t)b * D_ + d) * L_ + (L_ - 6) + t];

    float part[E_];
    #pragma unroll
    for (int e = 0; e < E_; ++e) part[e] = 0.f;
    #pragma unroll
    for (int t = 0; t < 5; ++t) {
        const float* wg = w_gate + (d * 5 + t) * E_;
        #pragma unroll
        for (int e = 0; e < E_; ++e) part[e] += xv[t] * wg[e];
    }
    #pragma unroll
    for (int off = 1; off < 64; off <<= 1) {
        #pragma unroll
        for (int e = 0; e < E_; ++e)
            part[e] += __shfl_xor(part[e], off, 64);
    }
    float m = part[0];
    #pragma unroll
    for (int e = 1; e < E_; ++e) m = fmaxf(m, part[e]);
    float p[E_], s = 0.f;
    #pragma unroll
    for (int e = 0; e < E_; ++e) { p[e] = expf(part[e] - m); s += p[e]; }
    float inv = 1.f / s;
    #pragma unroll
    for (int e = 0; e < E_; ++e) p[e] *= inv;

    int i0 = 0;
    #pragma unroll
    for (int e = 1; e < E_; ++e) if (p[e] > p[i0]) i0 = e;
    int i1 = (i0 == 0) ? 1 : 0;
    #pragma unroll
    for (int e = 0; e < E_; ++e) {
        if (e == i0) continue;
        if (p[e] > p[i1]) i1 = e;
    }
    const float v0 = p[i0], v1 = p[i1];
    const float den = v0 + v1 + 1e-6f;
    const float g0 = v0 / den, g1 = v1 / den;

    {
        const int dd = lane & 31, half = lane >> 5;
        #pragma unroll
        for (int ks = 0; ks < 2; ++ks) {
            #pragma unroll
            for (int i = 0; i < 8; ++i) {
                int oc = ks * 16 + half * 8 + i;
                float v = g0 * c2w[(dd * E_ + i0) * OC_ + oc]
                        + g1 * c2w[(dd * E_ + i1) * OC_ + oc];
                wf2[((b * 2 + ks) * 64 + lane) * 8 + i] = f2bf(v);
            }
        }
    }
    if (d < OC_)
        beff[b * OC_ + d] = g0 * c2b[d * E_ + i0] + g1 * c2b[d * E_ + i1];
}

// ---------------------------------------------------------------------------
// Compute one 256-col tile from a staged LDS buffer (per-wave 32-col group).
// ---------------------------------------------------------------------------
static __device__ __forceinline__ void compute_tile(
    const unsigned short* __restrict__ xbuf,
    const short8* a1, const short8* a2,
    const float* __restrict__ c1b,
    const float* __restrict__ be,
    float* __restrict__ outb,
    int l0, int wv, int cl, int hi)
{
    const int cb = wv * 32;
    float16 acc = (float16)0.0f;
    #pragma unroll
    for (int t = 0; t < 3; ++t) {
        int row = cb + cl + t;
        int rb  = row * 128;
        int swz = (row & 7) << 4;
        #pragma unroll
        for (int q = 0; q < 4; ++q) {
            int off = (rb + q * 32 + hi * 16) ^ swz;
            short8 bf = *(const short8*)((const char*)xbuf + off);
            acc = __builtin_amdgcn_mfma_f32_32x32x16_bf16(a1[t * 4 + q], bf, acc, 0, 0, 0);
        }
    }

    float th[16];
    #pragma unroll
    for (int r = 0; r < 16; ++r) {
        int row = (r & 3) + 8 * (r >> 2) + 4 * hi;
        th[r] = fast_tanh(acc[r] + c1b[row]);
    }

    unsigned x0a = hi ? cvtpk(th[0],  th[1])  : cvtpk(th[4],  th[5]);
    unsigned x0b = hi ? cvtpk(th[2],  th[3])  : cvtpk(th[6],  th[7]);
    unsigned x1a = hi ? cvtpk(th[8],  th[9])  : cvtpk(th[12], th[13]);
    unsigned x1b = hi ? cvtpk(th[10], th[11]) : cvtpk(th[14], th[15]);
    unsigned r0a = (unsigned)__shfl_xor((int)x0a, 32, 64);
    unsigned r0b = (unsigned)__shfl_xor((int)x0b, 32, 64);
    unsigned r1a = (unsigned)__shfl_xor((int)x1a, 32, 64);
    unsigned r1b = (unsigned)__shfl_xor((int)x1b, 32, 64);

    union U { short8 s8; unsigned u[4]; };
    U b0, b1;
    b0.u[0] = hi ? r0a : cvtpk(th[0], th[1]);
    b0.u[1] = hi ? r0b : cvtpk(th[2], th[3]);
    b0.u[2] = hi ? cvtpk(th[4], th[5]) : r0a;
    b0.u[3] = hi ? cvtpk(th[6], th[7]) : r0b;
    b1.u[0] = hi ? r1a : cvtpk(th[8], th[9]);
    b1.u[1] = hi ? r1b : cvtpk(th[10], th[11]);
    b1.u[2] = hi ? cvtpk(th[12], th[13]) : r1a;
    b1.u[3] = hi ? cvtpk(th[14], th[15]) : r1b;

    float16 acc2 = (float16)0.0f;
    acc2 = __builtin_amdgcn_mfma_f32_32x32x16_bf16(a2[0], b0.s8, acc2, 0, 0, 0);
    acc2 = __builtin_amdgcn_mfma_f32_32x32x16_bf16(a2[1], b1.s8, acc2, 0, 0, 0);

    int l = l0 + cb + cl;
    if (l < LP_) {
        float* ob = outb + l;
        #pragma unroll
        for (int r = 0; r < 16; ++r) {
            int row = (r & 3) + 8 * (r >> 2) + 4 * hi;
            ob[(size_t)row * LP_] = acc2[r] + be[row];
        }
    }
}

// ---------------------------------------------------------------------------
// Fused main v4: software-pipelined streaming (T14).
// Grid 256 blocks (1/CU) x 512 threads (8 waves). Block owns a 512-col strip
// = 2 tiles of 256. Double-buffered LDS; tile1's global loads are issued
// before tile0's compute so HBM latency/BW hides under MFMA+tanh+stores.
// ---------------------------------------------------------------------------
__global__ __launch_bounds__(512, 2)
void fused_main(const float* __restrict__ x,
                const unsigned short* __restrict__ aF,   // [12][64][8]
                const unsigned short* __restrict__ wf2,  // [B][2][64][8]
                const float* __restrict__ beff,          // [B][32]
                const float* __restrict__ c1b,           // [32]
                float* __restrict__ out)                 // [B][32][4094]
{
    // two buffers: bf16 [260 rows(l)][64 c], pitch 128 B, XOR-swizzle (row&7)<<4
    __shared__ __align__(16) unsigned short xT0[260 * 64];  // 33280 B
    __shared__ __align__(16) unsigned short xT1[260 * 64];  // 33280 B

    const int tid  = threadIdx.x;
    const int lane = tid & 63;
    const int wv   = tid >> 6;              // 0..7
    const int b    = blockIdx.x >> 3;
    const int S    = (blockIdx.x & 7) << 9; // strip base (0..3584)
    const float* xb = x + (size_t)b * (D_ * L_);

    // staging mapping: c2 = channel pair 0..31, jb = col offset
    const int c2 = tid >> 4;                // 0..31
    const int jb = (tid & 15) << 2;         // 0..60
    const float* p0 = xb + (size_t)(2 * c2) * L_;
    const float* p1 = p0 + L_;
    const int haloc = tid >> 1;             // halo: c-pair (tid<64)
    const int haloj = tid & 1;

    // ---- issue tile0 loads ----
    float4 A0[4], A1[4];
    #pragma unroll
    for (int jq = 0; jq < 4; ++jq) {
        int j = S + jq * 64 + jb;
        A0[jq] = *(const float4*)(p0 + j);
        A1[jq] = *(const float4*)(p1 + j);
    }
    float hA0 = 0.f, hA1 = 0.f;
    if (tid < 64) {
        int lg = S + 256 + haloj;           // always < 4096 (S <= 3584)
        hA0 = xb[(size_t)(2 * haloc) * L_ + lg];
        hA1 = xb[(size_t)(2 * haloc + 1) * L_ + lg];
    }

    // ---- per-block constants (L2-hot), overlap tile0 load latency ----
    short8 a1[12];
    #pragma unroll
    for (int ks = 0; ks < 12; ++ks)
        a1[ks] = *(const short8*)(aF + (ks * 64 + lane) * 8);
    short8 a2[2];
    a2[0] = *(const short8*)(wf2 + ((b * 2 + 0) * 64 + lane) * 8);
    a2[1] = *(const short8*)(wf2 + ((b * 2 + 1) * 64 + lane) * 8);
    const float* be = beff + b * OC_;
    float* outb = out + (size_t)b * (OC_ * (size_t)LP_);

    const int cl = lane & 31;
    const int hi = lane >> 5;

    // ---- write tile0 -> buf0 (waits tile0 vmcnt) ----
    #pragma unroll
    for (int jq = 0; jq < 4; ++jq) {
        float e0[4] = {A0[jq].x, A0[jq].y, A0[jq].z, A0[jq].w};
        float e1[4] = {A1[jq].x, A1[jq].y, A1[jq].z, A1[jq].w};
        #pragma unroll
        for (int r = 0; r < 4; ++r) {
            int row = jq * 64 + jb + r;
            int off = (row * 128 + c2 * 4) ^ ((row & 7) << 4);
            *(unsigned*)((char*)xT0 + off) = cvtpk(e0[r], e1[r]);
        }
    }
    if (tid < 64) {
        int row = 256 + haloj;
        int off = (row * 128 + haloc * 4) ^ ((row & 7) << 4);
        *(unsigned*)((char*)xT0 + off) = cvtpk(hA0, hA1);
    }

    // ---- issue tile1 loads (in flight across compute of tile0) ----
    float4 B0[4], B1[4];
    #pragma unroll
    for (int jq = 0; jq < 4; ++jq) {
        int j = S + 256 + jq * 64 + jb;
        B0[jq] = *(const float4*)(p0 + j);
        B1[jq] = *(const float4*)(p1 + j);
    }
    float hB0 = 0.f, hB1 = 0.f;
    if (tid < 64) {
        int lg = S + 512 + haloj;
        if (lg > L_ - 1) lg = L_ - 1;       // last strip: dead-output halo
        hB0 = xb[(size_t)(2 * haloc) * L_ + lg];
        hB1 = xb[(size_t)(2 * haloc + 1) * L_ + lg];
    }

    __syncthreads();

    // ---- compute tile0 (tile1 loads streaming underneath) ----
    compute_tile(xT0, a1, a2, c1b, be, outb, S, wv, cl, hi);

    __syncthreads();

    // ---- write tile1 -> buf1 ----
    #pragma unroll
    for (int jq = 0; jq < 4; ++jq) {
        float e0[4] = {B0[jq].x, B0[jq].y, B0[jq].z, B0[jq].w};
        float e1[4] = {B1[jq].x, B1[jq].y, B1[jq].z, B1[jq].w};
        #pragma unroll
        for (int r = 0; r < 4; ++r) {
            int row = jq * 64 + jb + r;
            int off = (row * 128 + c2 * 4) ^ ((row & 7) << 4);
            *(unsigned*)((char*)xT1 + off) = cvtpk(e0[r], e1[r]);
        }
    }
    if (tid < 64) {
        int row = 256 + haloj;
        int off = (row * 128 + haloc * 4) ^ ((row & 7) << 4);
        *(unsigned*)((char*)xT1 + off) = cvtpk(hB0, hB1);
    }

    __syncthreads();

    // ---- compute tile1 ----
    compute_tile(xT1, a1, a2, c1b, be, outb, S + 256, wv, cl, hi);
}

// ---------------------------------------------------------------------------
extern "C" void kernel_launch(void* const* d_in, const int* in_sizes, int n_in,
                              void* d_out, int out_size, void* d_ws, size_t ws_size,
                              hipStream_t stream)
{
    const float* x      = (const float*)d_in[0];
    const float* w_gate = (const float*)d_in[1];
    const float* c1w    = (const float*)d_in[2];
    const float* c1b    = (const float*)d_in[3];
    const float* c2w    = (const float*)d_in[4];
    const float* c2b    = (const float*)d_in[5];
    float* out = (float*)d_out;

    char* ws = (char*)d_ws;
    float* beff         = (float*)ws;                    // 4096 B
    unsigned short* aF  = (unsigned short*)(ws + 4096);  // 12288 B
    unsigned short* wf2 = (unsigned short*)(ws + 16384); // 65536 B

    prep_kernel<<<9, 256, 0, stream>>>(x, w_gate, c1w, c2w, c2b, beff, aF, wf2);
    fused_main<<<B_ * 8, 512, 0, stream>>>(x, aF, wf2, beff, c1b, out);
}

// Round 11
// 20.709 us; speedup vs baseline: 1.1377x; 1.0987x over previous
//
#include <hip/hip_runtime.h>
#include <math.h>

// Problem constants
#define B_  32
#define D_  64
#define L_  4096
#define E_  8
#define OC_ 32
#define LP_ 4094   // L - 2 (VALID conv, kernel 3)

typedef __attribute__((ext_vector_type(8)))  short short8;
typedef __attribute__((ext_vector_type(16))) float float16;

static __device__ __forceinline__ unsigned cvtpk(float a, float b) {
    unsigned r;
    asm("v_cvt_pk_bf16_f32 %0, %1, %2" : "=v"(r) : "v"(a), "v"(b));
    return r;
}
static __device__ __forceinline__ float fast_tanh(float x) {
    float e = __expf(2.0f * x);
    return fmaf(-2.0f, __builtin_amdgcn_rcpf(e + 1.0f), 1.0f);
}

// ---------------------------------------------------------------------------
// SINGLE kernel. Grid 256 blocks (1/CU) x 512 threads (8 waves).
// Block = (batch b = blk>>3, 512-col strip = 2 tiles of 256 cols).
// In-block prep (amortized over a 512-col strip, 8x less redundant than a
// per-128-tile version): gates (overlaps tile0 load latency), c1w -> LDS in
// MFMA A-fragment order (coalesced), conv2 Weff fragments from L2-hot c2w.
// Pipeline: issue(T0) -> prep -> write T0 -> issue(T1) -> bar ->
//           compute(T0) -> bar -> write T1 -> bar -> compute(T1).
// ---------------------------------------------------------------------------
__global__ __launch_bounds__(512, 1)
void fused_all(const float* __restrict__ x,
               const float* __restrict__ w_gate,  // [320][8]
               const float* __restrict__ c1w,     // [32][64][3]
               const float* __restrict__ c1b,     // [32]
               const float* __restrict__ c2w,     // [256][32]
               const float* __restrict__ c2b,     // [256]
               float* __restrict__ out);          // [B][32][4094]

static __device__ __forceinline__ void compute_tile(
    const unsigned short* __restrict__ xbuf,
    const short8* a1, const short8* a2,
    const float* __restrict__ c1b,
    const float* __restrict__ c2b,
    int i0, int i1, float g0, float g1,
    float* __restrict__ outb,
    int l0, int wv, int cl, int hi)
{
    const int cb = wv * 32;
    float16 acc = (float16)0.0f;
    #pragma unroll
    for (int t = 0; t < 3; ++t) {
        int row = cb + cl + t;
        int rb  = row * 128;
        int swz = (row & 7) << 4;
        #pragma unroll
        for (int q = 0; q < 4; ++q) {
            int off = (rb + q * 32 + hi * 16) ^ swz;
            short8 bf = *(const short8*)((const char*)xbuf + off);
            acc = __builtin_amdgcn_mfma_f32_32x32x16_bf16(a1[t * 4 + q], bf, acc, 0, 0, 0);
        }
    }

    float th[16];
    #pragma unroll
    for (int r = 0; r < 16; ++r) {
        int row = (r & 3) + 8 * (r >> 2) + 4 * hi;
        th[r] = fast_tanh(acc[r] + c1b[row]);
    }

    unsigned x0a = hi ? cvtpk(th[0],  th[1])  : cvtpk(th[4],  th[5]);
    unsigned x0b = hi ? cvtpk(th[2],  th[3])  : cvtpk(th[6],  th[7]);
    unsigned x1a = hi ? cvtpk(th[8],  th[9])  : cvtpk(th[12], th[13]);
    unsigned x1b = hi ? cvtpk(th[10], th[11]) : cvtpk(th[14], th[15]);
    unsigned r0a = (unsigned)__shfl_xor((int)x0a, 32, 64);
    unsigned r0b = (unsigned)__shfl_xor((int)x0b, 32, 64);
    unsigned r1a = (unsigned)__shfl_xor((int)x1a, 32, 64);
    unsigned r1b = (unsigned)__shfl_xor((int)x1b, 32, 64);

    union U { short8 s8; unsigned u[4]; };
    U b0, b1;
    b0.u[0] = hi ? r0a : cvtpk(th[0], th[1]);
    b0.u[1] = hi ? r0b : cvtpk(th[2], th[3]);
    b0.u[2] = hi ? cvtpk(th[4], th[5]) : r0a;
    b0.u[3] = hi ? cvtpk(th[6], th[7]) : r0b;
    b1.u[0] = hi ? r1a : cvtpk(th[8], th[9]);
    b1.u[1] = hi ? r1b : cvtpk(th[10], th[11]);
    b1.u[2] = hi ? cvtpk(th[12], th[13]) : r1a;
    b1.u[3] = hi ? cvtpk(th[14], th[15]) : r1b;

    float16 acc2 = (float16)0.0f;
    acc2 = __builtin_amdgcn_mfma_f32_32x32x16_bf16(a2[0], b0.s8, acc2, 0, 0, 0);
    acc2 = __builtin_amdgcn_mfma_f32_32x32x16_bf16(a2[1], b1.s8, acc2, 0, 0, 0);

    int l = l0 + cb + cl;
    if (l < LP_) {
        float* ob = outb + l;
        #pragma unroll
        for (int r = 0; r < 16; ++r) {
            int row = (r & 3) + 8 * (r >> 2) + 4 * hi;
            float bb = fmaf(g0, c2b[row * E_ + i0], g1 * c2b[row * E_ + i1]);
            ob[(size_t)row * LP_] = acc2[r] + bb;
        }
    }
}

__global__ __launch_bounds__(512, 1)
void fused_all(const float* __restrict__ x,
               const float* __restrict__ w_gate,
               const float* __restrict__ c1w,
               const float* __restrict__ c1b,
               const float* __restrict__ c2w,
               const float* __restrict__ c2b,
               float* __restrict__ out)
{
    // double-buffered x tiles: bf16 [260 rows][64 c], pitch 128 B, swizzled
    __shared__ __align__(16) unsigned short xT0[260 * 64];  // 33280 B
    __shared__ __align__(16) unsigned short xT1[260 * 64];  // 33280 B
    // conv1 A-fragments [12][64][8] bf16
    __shared__ __align__(16) unsigned short aFl[12 * 64 * 8]; // 12288 B

    const int tid  = threadIdx.x;
    const int lane = tid & 63;
    const int wv   = tid >> 6;              // 0..7
    const int b    = blockIdx.x >> 3;
    const int S    = (blockIdx.x & 7) << 9; // strip base 0..3584
    const float* xb = x + (size_t)b * (D_ * L_);

    // staging mapping
    const int c2 = tid >> 4;                // 0..31 channel pair
    const int jb = (tid & 15) << 2;         // 0..60
    const float* p0 = xb + (size_t)(2 * c2) * L_;
    const float* p1 = p0 + L_;
    const int haloc = tid >> 1;
    const int haloj = tid & 1;

    // ---- issue tile0 loads ----
    float4 A0[4], A1[4];
    #pragma unroll
    for (int jq = 0; jq < 4; ++jq) {
        int j = S + jq * 64 + jb;
        A0[jq] = *(const float4*)(p0 + j);
        A1[jq] = *(const float4*)(p1 + j);
    }
    float hA0 = 0.f, hA1 = 0.f;
    if (tid < 64) {
        int lg = S + 256 + haloj;           // <= 3841 < 4096
        hA0 = xb[(size_t)(2 * haloc) * L_ + lg];
        hA1 = xb[(size_t)(2 * haloc + 1) * L_ + lg];
    }

    // ---- issue c1w loads (coalesced; 12 consecutive floats/thread) ----
    const int w_oc = tid >> 4;              // 0..31
    const int w_c0 = (tid & 15) << 2;       // 0,4,..,60
    float wv12[12];
    {
        const float* wp = c1w + w_oc * 192 + w_c0 * 3;
        *(float4*)(wv12 + 0) = *(const float4*)(wp + 0);
        *(float4*)(wv12 + 4) = *(const float4*)(wp + 4);
        *(float4*)(wv12 + 8) = *(const float4*)(wp + 8);
    }

    // ---- gates (per-wave redundant; overlaps the loads above) ----
    int i0, i1;
    float g0, g1;
    {
        const int d = lane;
        float part[E_];
        #pragma unroll
        for (int e = 0; e < E_; ++e) part[e] = 0.f;
        #pragma unroll
        for (int t = 0; t < 5; ++t) {
            float xvt = xb[(size_t)d * L_ + (L_ - 6) + t];
            const float* wgp = w_gate + (d * 5 + t) * E_;
            float4 wa = *(const float4*)wgp;
            float4 wb = *(const float4*)(wgp + 4);
            part[0] = fmaf(xvt, wa.x, part[0]);
            part[1] = fmaf(xvt, wa.y, part[1]);
            part[2] = fmaf(xvt, wa.z, part[2]);
            part[3] = fmaf(xvt, wa.w, part[3]);
            part[4] = fmaf(xvt, wb.x, part[4]);
            part[5] = fmaf(xvt, wb.y, part[5]);
            part[6] = fmaf(xvt, wb.z, part[6]);
            part[7] = fmaf(xvt, wb.w, part[7]);
        }
        #pragma unroll
        for (int off = 1; off < 64; off <<= 1) {
            #pragma unroll
            for (int e = 0; e < E_; ++e)
                part[e] += __shfl_xor(part[e], off, 64);
        }
        float m = part[0];
        #pragma unroll
        for (int e = 1; e < E_; ++e) m = fmaxf(m, part[e]);
        float p[E_], s = 0.f;
        #pragma unroll
        for (int e = 0; e < E_; ++e) { p[e] = expf(part[e] - m); s += p[e]; }
        float inv = 1.f / s;
        #pragma unroll
        for (int e = 0; e < E_; ++e) p[e] *= inv;

        i0 = 0;
        #pragma unroll
        for (int e = 1; e < E_; ++e) if (p[e] > p[i0]) i0 = e;
        i1 = (i0 == 0) ? 1 : 0;
        #pragma unroll
        for (int e = 0; e < E_; ++e) {
            if (e == i0) continue;
            if (p[e] > p[i1]) i1 = e;
        }
        const float v0 = p[i0], v1 = p[i1];
        const float den = v0 + v1 + 1e-6f;
        g0 = v0 / den;
        g1 = v1 / den;
    }

    const int cl = lane & 31;
    const int hi = lane >> 5;

    // ---- conv2 Weff A-frags from L2-hot c2w ----
    short8 a2[2];
    #pragma unroll
    for (int ks = 0; ks < 2; ++ks) {
        const float* q0 = c2w + (cl * E_ + i0) * OC_ + ks * 16 + hi * 8;
        const float* q1 = c2w + (cl * E_ + i1) * OC_ + ks * 16 + hi * 8;
        float4 u0a = *(const float4*)q0, u0b = *(const float4*)(q0 + 4);
        float4 u1a = *(const float4*)q1, u1b = *(const float4*)(q1 + 4);
        union { short8 s8; unsigned u[4]; } f;
        f.u[0] = cvtpk(fmaf(g0, u0a.x, g1 * u1a.x), fmaf(g0, u0a.y, g1 * u1a.y));
        f.u[1] = cvtpk(fmaf(g0, u0a.z, g1 * u1a.z), fmaf(g0, u0a.w, g1 * u1a.w));
        f.u[2] = cvtpk(fmaf(g0, u0b.x, g1 * u1b.x), fmaf(g0, u0b.y, g1 * u1b.y));
        f.u[3] = cvtpk(fmaf(g0, u0b.z, g1 * u1b.z), fmaf(g0, u0b.w, g1 * u1b.w));
        a2[ks] = f.s8;
    }

    // ---- write c1w -> aFl in fragment order (2x b32 pack, 1x b64 store) ----
    // slot for (oc,c,t): kp=t*64+c; s=(t*4+(c0>>4))*64 + ((c0>>3)&1)*32 + oc;
    // 4 c-values (c0..c0+3) fill bf16 elements (c0&7)..(c0&7)+3 of slot s.
    {
        const int ksoff = w_c0 >> 4;
        const int half  = (w_c0 >> 3) & 1;
        const int ii0   = w_c0 & 7;           // 0 or 4
        #pragma unroll
        for (int t = 0; t < 3; ++t) {
            unsigned u0 = cvtpk(wv12[0 * 3 + t], wv12[1 * 3 + t]);
            unsigned u1 = cvtpk(wv12[2 * 3 + t], wv12[3 * 3 + t]);
            int base = ((t * 4 + ksoff) * 64 + half * 32 + w_oc) * 8 + ii0;
            uint2 w2 = {u0, u1};
            *(uint2*)(aFl + base) = w2;
        }
    }

    // ---- write tile0 -> xT0 ----
    #pragma unroll
    for (int jq = 0; jq < 4; ++jq) {
        float e0[4] = {A0[jq].x, A0[jq].y, A0[jq].z, A0[jq].w};
        float e1[4] = {A1[jq].x, A1[jq].y, A1[jq].z, A1[jq].w};
        #pragma unroll
        for (int r = 0; r < 4; ++r) {
            int row = jq * 64 + jb + r;
            int off = (row * 128 + c2 * 4) ^ ((row & 7) << 4);
            *(unsigned*)((char*)xT0 + off) = cvtpk(e0[r], e1[r]);
        }
    }
    if (tid < 64) {
        int row = 256 + haloj;
        int off = (row * 128 + haloc * 4) ^ ((row & 7) << 4);
        *(unsigned*)((char*)xT0 + off) = cvtpk(hA0, hA1);
    }

    // ---- issue tile1 loads (in flight across compute of tile0) ----
    float4 B0[4], B1[4];
    #pragma unroll
    for (int jq = 0; jq < 4; ++jq) {
        int j = S + 256 + jq * 64 + jb;
        B0[jq] = *(const float4*)(p0 + j);
        B1[jq] = *(const float4*)(p1 + j);
    }
    float hB0 = 0.f, hB1 = 0.f;
    if (tid < 64) {
        int lg = S + 512 + haloj;
        if (lg > L_ - 1) lg = L_ - 1;       // dead-output halo on last strip
        hB0 = xb[(size_t)(2 * haloc) * L_ + lg];
        hB1 = xb[(size_t)(2 * haloc + 1) * L_ + lg];
    }

    __syncthreads();

    // per-wave conv1 A-frags from LDS (contiguous b128, conflict-free)
    short8 a1[12];
    #pragma unroll
    for (int ks = 0; ks < 12; ++ks)
        a1[ks] = *(const short8*)(aFl + (ks * 64 + lane) * 8);

    float* outb = out + (size_t)b * (OC_ * (size_t)LP_);

    // ---- compute tile0 ----
    compute_tile(xT0, a1, a2, c1b, c2b, i0, i1, g0, g1, outb, S, wv, cl, hi);

    __syncthreads();

    // ---- write tile1 -> xT1 ----
    #pragma unroll
    for (int jq = 0; jq < 4; ++jq) {
        float e0[4] = {B0[jq].x, B0[jq].y, B0[jq].z, B0[jq].w};
        float e1[4] = {B1[jq].x, B1[jq].y, B1[jq].z, B1[jq].w};
        #pragma unroll
        for (int r = 0; r < 4; ++r) {
            int row = jq * 64 + jb + r;
            int off = (row * 128 + c2 * 4) ^ ((row & 7) << 4);
            *(unsigned*)((char*)xT1 + off) = cvtpk(e0[r], e1[r]);
        }
    }
    if (tid < 64) {
        int row = 256 + haloj;
        int off = (row * 128 + haloc * 4) ^ ((row & 7) << 4);
        *(unsigned*)((char*)xT1 + off) = cvtpk(hB0, hB1);
    }

    __syncthreads();

    // ---- compute tile1 ----
    compute_tile(xT1, a1, a2, c1b, c2b, i0, i1, g0, g1, outb, S + 256, wv, cl, hi);
}

// ---------------------------------------------------------------------------
extern "C" void kernel_launch(void* const* d_in, const int* in_sizes, int n_in,
                              void* d_out, int out_size, void* d_ws, size_t ws_size,
                              hipStream_t stream)
{
    const float* x      = (const float*)d_in[0];
    const float* w_gate = (const float*)d_in[1];
    const float* c1w    = (const float*)d_in[2];
    const float* c1b    = (const float*)d_in[3];
    const float* c2w    = (const float*)d_in[4];
    const float* c2b    = (const float*)d_in[5];
    float* out = (float*)d_out;

    fused_all<<<B_ * 8, 512, 0, stream>>>(x, w_gate, c1w, c1b, c2w, c2b, out);
}

// Round 12
// 19.203 us; speedup vs baseline: 1.2269x; 1.0784x over previous
//
#include <hip/hip_runtime.h>
#include <math.h>

// Problem constants
#define B_  32
#define D_  64
#define L_  4096
#define E_  8
#define OC_ 32
#define LP_ 4094   // L - 2 (VALID conv, kernel 3)

typedef __attribute__((ext_vector_type(8)))  short short8;
typedef __attribute__((ext_vector_type(16))) float float16;

static __device__ __forceinline__ unsigned cvtpk(float a, float b) {
    unsigned r;
    asm("v_cvt_pk_bf16_f32 %0, %1, %2" : "=v"(r) : "v"(a), "v"(b));
    return r;
}
static __device__ __forceinline__ float fast_tanh(float x) {
    float e = __expf(2.0f * x);
    return fmaf(-2.0f, __builtin_amdgcn_rcpf(e + 1.0f), 1.0f);
}

// ---------------------------------------------------------------------------
// SINGLE kernel. Grid 256 blocks (1/CU) x 512 threads (8 waves).
// Block = (batch b = blk>>3, 512-col strip = 2 tiles of 256 cols).
// Delta vs R11: gates + conv2-Weff-fragment construction run in WAVE 0 ONLY
// (they are lane-identical across waves); results broadcast via LDS at the
// existing barrier. Removes 7/8 of the uncoalesced TA-serialized gathers
// from every block's prologue critical path.
// ---------------------------------------------------------------------------
static __device__ __forceinline__ void compute_tile(
    const unsigned short* __restrict__ xbuf,
    const short8* a1, const short8* a2,
    const float* __restrict__ c1b,
    const float* __restrict__ c2b,
    int i0, int i1, float g0, float g1,
    float* __restrict__ outb,
    int l0, int wv, int cl, int hi)
{
    const int cb = wv * 32;
    float16 acc = (float16)0.0f;
    #pragma unroll
    for (int t = 0; t < 3; ++t) {
        int row = cb + cl + t;
        int rb  = row * 128;
        int swz = (row & 7) << 4;
        #pragma unroll
        for (int q = 0; q < 4; ++q) {
            int off = (rb + q * 32 + hi * 16) ^ swz;
            short8 bf = *(const short8*)((const char*)xbuf + off);
            acc = __builtin_amdgcn_mfma_f32_32x32x16_bf16(a1[t * 4 + q], bf, acc, 0, 0, 0);
        }
    }

    float th[16];
    #pragma unroll
    for (int r = 0; r < 16; ++r) {
        int row = (r & 3) + 8 * (r >> 2) + 4 * hi;
        th[r] = fast_tanh(acc[r] + c1b[row]);
    }

    unsigned x0a = hi ? cvtpk(th[0],  th[1])  : cvtpk(th[4],  th[5]);
    unsigned x0b = hi ? cvtpk(th[2],  th[3])  : cvtpk(th[6],  th[7]);
    unsigned x1a = hi ? cvtpk(th[8],  th[9])  : cvtpk(th[12], th[13]);
    unsigned x1b = hi ? cvtpk(th[10], th[11]) : cvtpk(th[14], th[15]);
    unsigned r0a = (unsigned)__shfl_xor((int)x0a, 32, 64);
    unsigned r0b = (unsigned)__shfl_xor((int)x0b, 32, 64);
    unsigned r1a = (unsigned)__shfl_xor((int)x1a, 32, 64);
    unsigned r1b = (unsigned)__shfl_xor((int)x1b, 32, 64);

    union U { short8 s8; unsigned u[4]; };
    U b0, b1;
    b0.u[0] = hi ? r0a : cvtpk(th[0], th[1]);
    b0.u[1] = hi ? r0b : cvtpk(th[2], th[3]);
    b0.u[2] = hi ? cvtpk(th[4], th[5]) : r0a;
    b0.u[3] = hi ? cvtpk(th[6], th[7]) : r0b;
    b1.u[0] = hi ? r1a : cvtpk(th[8], th[9]);
    b1.u[1] = hi ? r1b : cvtpk(th[10], th[11]);
    b1.u[2] = hi ? cvtpk(th[12], th[13]) : r1a;
    b1.u[3] = hi ? cvtpk(th[14], th[15]) : r1b;

    float16 acc2 = (float16)0.0f;
    acc2 = __builtin_amdgcn_mfma_f32_32x32x16_bf16(a2[0], b0.s8, acc2, 0, 0, 0);
    acc2 = __builtin_amdgcn_mfma_f32_32x32x16_bf16(a2[1], b1.s8, acc2, 0, 0, 0);

    int l = l0 + cb + cl;
    if (l < LP_) {
        float* ob = outb + l;
        #pragma unroll
        for (int r = 0; r < 16; ++r) {
            int row = (r & 3) + 8 * (r >> 2) + 4 * hi;
            float bb = fmaf(g0, c2b[row * E_ + i0], g1 * c2b[row * E_ + i1]);
            ob[(size_t)row * LP_] = acc2[r] + bb;
        }
    }
}

__global__ __launch_bounds__(512, 1)
void fused_all(const float* __restrict__ x,
               const float* __restrict__ w_gate,  // [320][8]
               const float* __restrict__ c1w,     // [32][64][3]
               const float* __restrict__ c1b,     // [32]
               const float* __restrict__ c2w,     // [256][32]
               const float* __restrict__ c2b,     // [256]
               float* __restrict__ out)           // [B][32][4094]
{
    __shared__ __align__(16) unsigned short xT0[260 * 64];    // 33280 B
    __shared__ __align__(16) unsigned short xT1[260 * 64];    // 33280 B
    __shared__ __align__(16) unsigned short aFl[12 * 64 * 8]; // 12288 B
    __shared__ __align__(16) unsigned short a2L[2 * 64 * 8];  //  2048 B
    __shared__ float  gF[2];   // g0, g1
    __shared__ int    gI[2];   // i0, i1

    const int tid  = threadIdx.x;
    const int lane = tid & 63;
    const int wv   = tid >> 6;              // 0..7
    const int b    = blockIdx.x >> 3;
    const int S    = (blockIdx.x & 7) << 9; // strip base 0..3584
    const float* xb = x + (size_t)b * (D_ * L_);

    // staging mapping
    const int c2 = tid >> 4;                // 0..31 channel pair
    const int jb = (tid & 15) << 2;         // 0..60
    const float* p0 = xb + (size_t)(2 * c2) * L_;
    const float* p1 = p0 + L_;
    const int haloc = tid >> 1;
    const int haloj = tid & 1;

    // ---- issue tile0 loads ----
    float4 A0[4], A1[4];
    #pragma unroll
    for (int jq = 0; jq < 4; ++jq) {
        int j = S + jq * 64 + jb;
        A0[jq] = *(const float4*)(p0 + j);
        A1[jq] = *(const float4*)(p1 + j);
    }
    float hA0 = 0.f, hA1 = 0.f;
    if (tid < 64) {
        int lg = S + 256 + haloj;           // <= 3841 < 4096
        hA0 = xb[(size_t)(2 * haloc) * L_ + lg];
        hA1 = xb[(size_t)(2 * haloc + 1) * L_ + lg];
    }

    // ---- issue c1w loads (coalesced; 12 consecutive floats/thread) ----
    const int w_oc = tid >> 4;              // 0..31
    const int w_c0 = (tid & 15) << 2;       // 0,4,..,60
    float wv12[12];
    {
        const float* wp = c1w + w_oc * 192 + w_c0 * 3;
        *(float4*)(wv12 + 0) = *(const float4*)(wp + 0);
        *(float4*)(wv12 + 4) = *(const float4*)(wp + 4);
        *(float4*)(wv12 + 8) = *(const float4*)(wp + 8);
    }

    // ---- WAVE 0 ONLY: gates + conv2 Weff fragments -> LDS broadcast ----
    if (wv == 0) {
        const int d = lane;
        float part[E_];
        #pragma unroll
        for (int e = 0; e < E_; ++e) part[e] = 0.f;
        #pragma unroll
        for (int t = 0; t < 5; ++t) {
            float xvt = xb[(size_t)d * L_ + (L_ - 6) + t];
            const float* wgp = w_gate + (d * 5 + t) * E_;
            float4 wa = *(const float4*)wgp;
            float4 wb = *(const float4*)(wgp + 4);
            part[0] = fmaf(xvt, wa.x, part[0]);
            part[1] = fmaf(xvt, wa.y, part[1]);
            part[2] = fmaf(xvt, wa.z, part[2]);
            part[3] = fmaf(xvt, wa.w, part[3]);
            part[4] = fmaf(xvt, wb.x, part[4]);
            part[5] = fmaf(xvt, wb.y, part[5]);
            part[6] = fmaf(xvt, wb.z, part[6]);
            part[7] = fmaf(xvt, wb.w, part[7]);
        }
        #pragma unroll
        for (int off = 1; off < 64; off <<= 1) {
            #pragma unroll
            for (int e = 0; e < E_; ++e)
                part[e] += __shfl_xor(part[e], off, 64);
        }
        float m = part[0];
        #pragma unroll
        for (int e = 1; e < E_; ++e) m = fmaxf(m, part[e]);
        float p[E_], s = 0.f;
        #pragma unroll
        for (int e = 0; e < E_; ++e) { p[e] = expf(part[e] - m); s += p[e]; }
        float inv = 1.f / s;
        #pragma unroll
        for (int e = 0; e < E_; ++e) p[e] *= inv;

        int i0 = 0;
        #pragma unroll
        for (int e = 1; e < E_; ++e) if (p[e] > p[i0]) i0 = e;
        int i1 = (i0 == 0) ? 1 : 0;
        #pragma unroll
        for (int e = 0; e < E_; ++e) {
            if (e == i0) continue;
            if (p[e] > p[i1]) i1 = e;
        }
        const float v0 = p[i0], v1 = p[i1];
        const float den = v0 + v1 + 1e-6f;
        const float g0 = v0 / den, g1 = v1 / den;

        const int cl0 = lane & 31;
        const int hi0 = lane >> 5;
        #pragma unroll
        for (int ks = 0; ks < 2; ++ks) {
            const float* q0 = c2w + (cl0 * E_ + i0) * OC_ + ks * 16 + hi0 * 8;
            const float* q1 = c2w + (cl0 * E_ + i1) * OC_ + ks * 16 + hi0 * 8;
            float4 u0a = *(const float4*)q0, u0b = *(const float4*)(q0 + 4);
            float4 u1a = *(const float4*)q1, u1b = *(const float4*)(q1 + 4);
            union { short8 s8; unsigned u[4]; } f;
            f.u[0] = cvtpk(fmaf(g0, u0a.x, g1 * u1a.x), fmaf(g0, u0a.y, g1 * u1a.y));
            f.u[1] = cvtpk(fmaf(g0, u0a.z, g1 * u1a.z), fmaf(g0, u0a.w, g1 * u1a.w));
            f.u[2] = cvtpk(fmaf(g0, u0b.x, g1 * u1b.x), fmaf(g0, u0b.y, g1 * u1b.y));
            f.u[3] = cvtpk(fmaf(g0, u0b.z, g1 * u1b.z), fmaf(g0, u0b.w, g1 * u1b.w));
            *(short8*)(a2L + (ks * 64 + lane) * 8) = f.s8;
        }
        if (lane == 0) {
            gF[0] = g0; gF[1] = g1;
            gI[0] = i0; gI[1] = i1;
        }
    }

    // ---- write c1w -> aFl in fragment order ----
    {
        const int ksoff = w_c0 >> 4;
        const int half  = (w_c0 >> 3) & 1;
        const int ii0   = w_c0 & 7;           // 0 or 4
        #pragma unroll
        for (int t = 0; t < 3; ++t) {
            unsigned u0 = cvtpk(wv12[0 * 3 + t], wv12[1 * 3 + t]);
            unsigned u1 = cvtpk(wv12[2 * 3 + t], wv12[3 * 3 + t]);
            int base = ((t * 4 + ksoff) * 64 + half * 32 + w_oc) * 8 + ii0;
            uint2 w2 = {u0, u1};
            *(uint2*)(aFl + base) = w2;
        }
    }

    // ---- write tile0 -> xT0 ----
    #pragma unroll
    for (int jq = 0; jq < 4; ++jq) {
        float e0[4] = {A0[jq].x, A0[jq].y, A0[jq].z, A0[jq].w};
        float e1[4] = {A1[jq].x, A1[jq].y, A1[jq].z, A1[jq].w};
        #pragma unroll
        for (int r = 0; r < 4; ++r) {
            int row = jq * 64 + jb + r;
            int off = (row * 128 + c2 * 4) ^ ((row & 7) << 4);
            *(unsigned*)((char*)xT0 + off) = cvtpk(e0[r], e1[r]);
        }
    }
    if (tid < 64) {
        int row = 256 + haloj;
        int off = (row * 128 + haloc * 4) ^ ((row & 7) << 4);
        *(unsigned*)((char*)xT0 + off) = cvtpk(hA0, hA1);
    }

    // ---- issue tile1 loads (in flight across compute of tile0) ----
    float4 B0[4], B1[4];
    #pragma unroll
    for (int jq = 0; jq < 4; ++jq) {
        int j = S + 256 + jq * 64 + jb;
        B0[jq] = *(const float4*)(p0 + j);
        B1[jq] = *(const float4*)(p1 + j);
    }
    float hB0 = 0.f, hB1 = 0.f;
    if (tid < 64) {
        int lg = S + 512 + haloj;
        if (lg > L_ - 1) lg = L_ - 1;       // dead-output halo on last strip
        hB0 = xb[(size_t)(2 * haloc) * L_ + lg];
        hB1 = xb[(size_t)(2 * haloc + 1) * L_ + lg];
    }

    __syncthreads();

    // ---- read broadcast prep results ----
    const int cl = lane & 31;
    const int hi = lane >> 5;
    short8 a1[12];
    #pragma unroll
    for (int ks = 0; ks < 12; ++ks)
        a1[ks] = *(const short8*)(aFl + (ks * 64 + lane) * 8);
    short8 a2[2];
    a2[0] = *(const short8*)(a2L + (0 * 64 + lane) * 8);
    a2[1] = *(const short8*)(a2L + (1 * 64 + lane) * 8);
    const float g0 = gF[0], g1 = gF[1];
    const int   i0 = gI[0], i1 = gI[1];

    float* outb = out + (size_t)b * (OC_ * (size_t)LP_);

    // ---- compute tile0 ----
    compute_tile(xT0, a1, a2, c1b, c2b, i0, i1, g0, g1, outb, S, wv, cl, hi);

    __syncthreads();

    // ---- write tile1 -> xT1 ----
    #pragma unroll
    for (int jq = 0; jq < 4; ++jq) {
        float e0[4] = {B0[jq].x, B0[jq].y, B0[jq].z, B0[jq].w};
        float e1[4] = {B1[jq].x, B1[jq].y, B1[jq].z, B1[jq].w};
        #pragma unroll
        for (int r = 0; r < 4; ++r) {
            int row = jq * 64 + jb + r;
            int off = (row * 128 + c2 * 4) ^ ((row & 7) << 4);
            *(unsigned*)((char*)xT1 + off) = cvtpk(e0[r], e1[r]);
        }
    }
    if (tid < 64) {
        int row = 256 + haloj;
        int off = (row * 128 + haloc * 4) ^ ((row & 7) << 4);
        *(unsigned*)((char*)xT1 + off) = cvtpk(hB0, hB1);
    }

    __syncthreads();

    // ---- compute tile1 ----
    compute_tile(xT1, a1, a2, c1b, c2b, i0, i1, g0, g1, outb, S + 256, wv, cl, hi);
}

// ---------------------------------------------------------------------------
extern "C" void kernel_launch(void* const* d_in, const int* in_sizes, int n_in,
                              void* d_out, int out_size, void* d_ws, size_t ws_size,
                              hipStream_t stream)
{
    const float* x      = (const float*)d_in[0];
    const float* w_gate = (const float*)d_in[1];
    const float* c1w    = (const float*)d_in[2];
    const float* c1b    = (const float*)d_in[3];
    const float* c2w    = (const float*)d_in[4];
    const float* c2b    = (const float*)d_in[5];
    float* out = (float*)d_out;

    fused_all<<<B_ * 8, 512, 0, stream>>>(x, w_gate, c1w, c1b, c2w, c2b, out);
}